// Round 10
// baseline (905.365 us; speedup 1.0000x reference)
//
#include <hip/hip_runtime.h>
#include <stdint.h>

typedef unsigned short u16;
typedef unsigned int   u32;
typedef __attribute__((ext_vector_type(8))) short short8;
typedef __attribute__((ext_vector_type(4))) float f32x4;
typedef __attribute__((ext_vector_type(16))) float f32x16;
typedef __attribute__((ext_vector_type(2))) unsigned int uint2v;

#define B_   8
#define S_   1024
#define DIN_ 512
#define H_   1024
#define NH_  16
#define HD_  64
#define L_   4
#define M_   (B_*S_)
#define SCALE_ 0.125f
#define LOG2E_ 1.44269504088896f
#define EPS_ 1e-5f

__device__ __forceinline__ u16 f2b(float f) {
  u32 u = __builtin_bit_cast(u32, f);
  u32 r = (u + 0x7fffu + ((u >> 16) & 1u)) >> 16;
  return (u16)r;
}

__device__ __forceinline__ u32 cvtpk(float lo, float hi) {
  u32 r;
  asm("v_cvt_pk_bf16_f32 %0, %1, %2" : "=v"(r) : "v"(lo), "v"(hi));
  return r;
}

__device__ __forceinline__ void gll16(const void* g, void* l) {
  __builtin_amdgcn_global_load_lds(
      (const __attribute__((address_space(1))) u32*)(uintptr_t)g,
      (__attribute__((address_space(3))) u32*)(uintptr_t)l,
      16, 0, 0);
}

// ---------------- fp32 -> bf16 flat convert (4 elems/thread) ----------------
__global__ void cvt_k(const float* __restrict__ in, u16* __restrict__ out) {
  long i = (long)(blockIdx.x * 256 + threadIdx.x) * 4;
  f32x4 v = *(const f32x4*)&in[i];
  u32 p0 = (u32)f2b(v[0]) | ((u32)f2b(v[1]) << 16);
  u32 p1 = (u32)f2b(v[2]) | ((u32)f2b(v[3]) << 16);
  u32* o = (u32*)&out[i];
  o[0] = p0; o[1] = p1;
}

// -------- fp32 [R,C] -> bf16 [C,R] transpose-convert, batched over z --------
__global__ __launch_bounds__(256)
void tcvt_k(const float* __restrict__ in0, u16* __restrict__ out0, int R, int C) {
  __shared__ float t[32][33];
  const float* in = in0 + (size_t)blockIdx.z * R * C;
  u16* out = out0 + (size_t)blockIdx.z * R * C;
  int tx = threadIdx.x & 31, ty = threadIdx.x >> 5;
  long r0 = blockIdx.y * 32, c0 = blockIdx.x * 32;
#pragma unroll
  for (int i = 0; i < 4; ++i)
    t[ty + i*8][tx] = in[(r0 + ty + i*8) * (long)C + c0 + tx];
  __syncthreads();
#pragma unroll
  for (int i = 0; i < 4; ++i)
    out[(c0 + ty + i*8) * (long)R + r0 + tx] = f2b(t[tx][ty + i*8]);
}

// ---------------- 128x128 GEMM (in-proj / O-proj): simple 2-barrier --------
template<int EPI>
__global__ __launch_bounds__(256, 2)
void gemm_k(const u16* __restrict__ A, const u16* __restrict__ Bt,
            const float* __restrict__ bias,
            float* __restrict__ Cf, u16* __restrict__ Cb,
            const float* __restrict__ Res,
            int Ndim, int K, int scale_cols)
{
  __shared__ u16 As[128 * 32];
  __shared__ u16 Bs[128 * 32];
  const int tid = threadIdx.x;
  const int lane = tid & 63;
  const int wid = tid >> 6;
  const int wr = wid >> 1, wc = wid & 1;
  const int l15 = lane & 15, l4 = lane >> 4;
  const long arow0 = (long)blockIdx.x * 128;
  const long brow0 = (long)blockIdx.y * 128;

  f32x4 acc[4][4] = {};

  const int srow = tid >> 2;
  const int scol = (tid & 3) * 8;
  const u16* ga  = A  + (arow0 + srow) * K + scol;
  const u16* ga1 = ga + 64 * (long)K;
  const u16* gb  = Bt + (brow0 + srow) * K + scol;
  const u16* gb1 = gb + 64 * (long)K;
  u16* lA0 = &As[tid * 8];
  u16* lA1 = &As[2048 + tid * 8];
  u16* lB0 = &Bs[tid * 8];
  u16* lB1 = &Bs[2048 + tid * 8];

  for (int k0 = 0; k0 < K; k0 += 32) {
    gll16(ga + k0, lA0);
    gll16(ga1 + k0, lA1);
    gll16(gb + k0, lB0);
    gll16(gb1 + k0, lB1);
    __syncthreads();
    short8 af[4], bf[4];
#pragma unroll
    for (int m = 0; m < 4; ++m)
      af[m] = *(const short8*)&As[(wr*64 + m*16 + l15) * 32 + l4*8];
#pragma unroll
    for (int n = 0; n < 4; ++n)
      bf[n] = *(const short8*)&Bs[(wc*64 + n*16 + l15) * 32 + l4*8];
#pragma unroll
    for (int m = 0; m < 4; ++m)
#pragma unroll
      for (int n = 0; n < 4; ++n)
        acc[m][n] = __builtin_amdgcn_mfma_f32_16x16x32_bf16(af[m], bf[n], acc[m][n], 0, 0, 0);
    __syncthreads();
  }

  const int crow = wr*64 + l4*4;
  const int ccol = wc*64 + l15;
#pragma unroll
  for (int m = 0; m < 4; ++m) {
#pragma unroll
    for (int n = 0; n < 4; ++n) {
      const int col = (int)brow0 + ccol + n*16;
      const float bv = bias[col];
      const float sc = (EPI == 1 && col < scale_cols) ? SCALE_ : 1.0f;
#pragma unroll
      for (int r = 0; r < 4; ++r) {
        const long row = arow0 + crow + m*16 + r;
        float v = acc[m][n][r] + bv;
        if (EPI == 1) {
          Cb[row * Ndim + col] = f2b(v * sc);
        } else if (EPI == 0) {
          Cf[row * Ndim + col] = v;
          Cb[row * Ndim + col] = f2b(v);
        } else {
          Cf[row * Ndim + col] = v + Res[row * Ndim + col];
        }
      }
    }
  }
}

// ---------------- 256x256 8-phase GEMM for QKV (M=8192,N=3072,K=1024) -------
// Q columns pre-scaled by SCALE_*log2(e) so attention works in exp2 domain.
__global__ __launch_bounds__(512, 1)
void gemm8_k(const u16* __restrict__ A, const u16* __restrict__ Bt,
             const float* __restrict__ bias, u16* __restrict__ Cb)
{
  constexpr int K = 1024, N = 3 * H_;
  constexpr int NT = K / 64;                 // 16 K-tiles
  __shared__ u16 lds[8][8192];               // [buf*4 + op*2 + half][128*64]

  const int tid = threadIdx.x;
  const int lane = tid & 63;
  const int wid = tid >> 6;
  const int wm = wid >> 2, wn = wid & 3;
  const int l15 = lane & 15, l4 = lane >> 4;

  const int bid = blockIdx.x;                // 384 blocks
  const int xcd = bid & 7, idx = bid >> 3;   // XCD owns arow strip of 4
  const long arow0 = (long)(xcd * 4 + (idx & 3)) * 256;
  const long brow0 = (long)(idx >> 2) * 256;

  f32x4 acc[8][4] = {};
  short8 bfr[4][2];
  short8 afr[2][2];

  auto stage = [&](int buf, int op, int half, int kt) {
    const u16* src = op ? Bt : A;
    const long rb = (op ? brow0 : arow0) + half * 128;
    u16* dst = lds[buf*4 + op*2 + half];
#pragma unroll
    for (int ld = 0; ld < 2; ++ld) {
      int p = ld * 512 + tid;
      int row = p >> 3;
      int kc = (p & 7) ^ (row & 7);          // inverse swizzle on source
      gll16(src + (rb + row) * (long)K + kt * 64 + kc * 8, (char*)dst + p * 16);
    }
  };
  auto readB = [&](int buf) {
    const char* base = (const char*)lds[buf*4 + 2 + (wn >> 1)];
#pragma unroll
    for (int n = 0; n < 4; ++n)
#pragma unroll
      for (int ks = 0; ks < 2; ++ks) {
        int rh = (wn & 1) * 64 + n * 16 + l15;
        int byt = rh * 128 + ((((ks*4 + l4) * 16)) ^ ((rh & 7) << 4));
        bfr[n][ks] = *(const short8*)(base + byt);
      }
  };
  auto readA = [&](int buf, int q) {
    const char* base = (const char*)lds[buf*4 + wm];
#pragma unroll
    for (int j = 0; j < 2; ++j)
#pragma unroll
      for (int ks = 0; ks < 2; ++ks) {
        int rh = (2*q + j) * 16 + l15;
        int byt = rh * 128 + ((((ks*4 + l4) * 16)) ^ ((rh & 7) << 4));
        afr[j][ks] = *(const short8*)(base + byt);
      }
  };
  auto mm = [&](int q) {
    __builtin_amdgcn_s_setprio(1);
#pragma unroll
    for (int j = 0; j < 2; ++j)
#pragma unroll
      for (int n = 0; n < 4; ++n)
#pragma unroll
        for (int ks = 0; ks < 2; ++ks)
          acc[2*q+j][n] = __builtin_amdgcn_mfma_f32_16x16x32_bf16(
              afr[j][ks], bfr[n][ks], acc[2*q+j][n], 0, 0, 0);
    __builtin_amdgcn_s_setprio(0);
  };

#define PH(cb, q, doB, sb, so, sh, st, doV)                       \
    readA(cb, q); if (doB) readB(cb);                             \
    stage(sb, so, sh, st);                                        \
    __builtin_amdgcn_s_barrier();                                 \
    mm(q);                                                        \
    if (doV) asm volatile("s_waitcnt vmcnt(6)" ::: "memory");     \
    __builtin_amdgcn_s_barrier();

  // prologue: B0,B1,A0,A1(tile0)->buf0; B0,B1,A0(tile1)->buf1  (7 half-tiles)
  stage(0,1,0,0); stage(0,1,1,0); stage(0,0,0,0); stage(0,0,1,0);
  stage(1,1,0,1); stage(1,1,1,1); stage(1,0,0,1);
  asm volatile("s_waitcnt vmcnt(6)" ::: "memory");   // buf0 (tile0) landed
  __builtin_amdgcn_s_barrier();

  const int niter = NT / 2;
  for (int i = 0; i < niter; ++i) {
    const int tO  = 2*i + 1;
    const int tE2 = (2*i + 2 < NT) ? 2*i + 2 : NT - 1;
    const int tO2 = (2*i + 3 < NT) ? 2*i + 3 : NT - 1;
    PH(0, 0, true , 1, 0, 1, tO , false)
    PH(0, 1, false, 0, 1, 0, tE2, false)
    PH(0, 2, false, 0, 1, 1, tE2, false)
    PH(0, 3, false, 0, 0, 0, tE2, true )
    PH(1, 0, true , 0, 0, 1, tE2, false)
    PH(1, 1, false, 1, 1, 0, tO2, false)
    PH(1, 2, false, 1, 1, 1, tO2, false)
    PH(1, 3, false, 1, 0, 0, tO2, true )
  }
#undef PH

  const long crow0 = arow0 + wm * 128;
  const int  ccol0 = (int)brow0 + wn * 64;
#pragma unroll
  for (int m = 0; m < 8; ++m) {
#pragma unroll
    for (int n = 0; n < 4; ++n) {
      const int col = ccol0 + n * 16 + l15;
      const float bv = bias[col];
      const float sc = (col < H_) ? (SCALE_ * LOG2E_) : 1.0f;
#pragma unroll
      for (int r = 0; r < 4; ++r) {
        const long row = crow0 + m * 16 + l4 * 4 + r;
        Cb[row * N + col] = f2b((acc[m][n][r] + bv) * sc);
      }
    }
  }
}

// ------------- flash attention v4: 4-wave blocks, tree softmax, exp2 --------
// grid: 1024 blocks x 256 threads (4 waves x 32 q-rows = 128 q/block);
// 4 blocks/CU for cross-block latency hiding. Q pre-scaled by SCALE*log2e.
__global__ __launch_bounds__(256)
void attn_k(const u16* __restrict__ qkv, u16* __restrict__ ob)
{
  __shared__ u16 Ks[2][4096];   // [64 kv][64 d], XOR-swizzled content
  __shared__ u16 Vs[2][4096];   // [64 d][64 kv] transposed, XOR-swizzled

  const int tid = threadIdx.x, lane = tid & 63, wid = tid >> 6;
  const int l31 = lane & 31, hi = lane >> 5;

  const int blk = blockIdx.x;                // 1024
  const int xcd = blk & 7, slot = blk >> 3;  // 0..127
  const int bh = xcd + ((slot >> 3) << 3);   // head 0..127
  const int qx = slot & 7;                   // q-tile 0..7 (128 rows each)
  const int b = bh >> 4, nh = bh & 15;
  const int q0 = qx * 128 + wid * 32;

  const int RS = 3 * H_;
  const long base = (long)b * S_ * RS;
  const u16* Qg = qkv + base + nh * HD_;
  const u16* Kg = qkv + base + H_ + nh * HD_;
  const u16* Vg = qkv + base + 2 * H_ + nh * HD_;

  short8 qf[4];
#pragma unroll
  for (int ks = 0; ks < 4; ++ks)
    qf[ks] = *(const short8*)&Qg[(long)(q0 + l31) * RS + ks*16 + hi*8];

  float m_ = -1e30f, l_ = 0.f;
  f32x16 o0 = {}, o1 = {};

  // staging: K via 2x gll16/thread (pre-swizzled source), V via 16 scalar loads
  const int kr0 = tid >> 3, kc0 = (tid & 7) ^ (kr0 & 7);
  const int kr1 = (256 + tid) >> 3, kc1 = (tid & 7) ^ (kr1 & 7);
  const long kg0 = (long)kr0 * RS + kc0 * 8;
  const long kg1 = (long)kr1 * RS + kc1 * 8;
  const int vd = tid & 63, vch = tid >> 6;   // vch 0..3
  const int vbyt0 = (vd*128 + vch*16) ^ ((vd & 7) << 4);
  const int vbyt1 = (vd*128 + 64 + vch*16) ^ ((vd & 7) << 4);

  {
    gll16(Kg + kg0, (char*)&Ks[0][0] + tid*16);
    gll16(Kg + kg1, (char*)&Ks[0][0] + (256 + tid)*16);
    union { u16 u[8]; short8 v; } ta, tb;
#pragma unroll
    for (int j = 0; j < 8; ++j) {
      ta.u[j] = Vg[(long)(vch*8 + j) * RS + vd];
      tb.u[j] = Vg[(long)(32 + vch*8 + j) * RS + vd];
    }
    *(short8*)((char*)&Vs[0][0] + vbyt0) = ta.v;
    *(short8*)((char*)&Vs[0][0] + vbyt1) = tb.v;
  }
  __syncthreads();

  for (int t = 0; t < 16; ++t) {
    const int cur = t & 1, nxt = cur ^ 1;
    union { u16 u[8]; short8 v; } ta, tb;
    if (t < 15) {
      const long kv1 = (long)(t + 1) * 64;
      gll16(Kg + kv1 * RS + kg0, (char*)&Ks[nxt][0] + tid*16);
      gll16(Kg + kv1 * RS + kg1, (char*)&Ks[nxt][0] + (256 + tid)*16);
#pragma unroll
      for (int j = 0; j < 8; ++j) {
        ta.u[j] = Vg[(kv1 + vch*8 + j) * RS + vd];
        tb.u[j] = Vg[(kv1 + 32 + vch*8 + j) * RS + vd];
      }
    }

    // ==== QK^T (exp2-domain scores) ====
    f32x16 s0 = {}, s1 = {};
    __builtin_amdgcn_s_setprio(1);
#pragma unroll
    for (int ks = 0; ks < 4; ++ks) {
      const int koff = ks*32 + hi*16;
      const int by0 = (l31*128 + koff) ^ ((l31 & 7) << 4);
      short8 kf0 = *(const short8*)((const char*)&Ks[cur][0] + by0);
      s0 = __builtin_amdgcn_mfma_f32_32x32x16_bf16(kf0, qf[ks], s0, 0, 0, 0);
      const int by1 = ((32 + l31)*128 + koff) ^ ((l31 & 7) << 4);
      short8 kf1 = *(const short8*)((const char*)&Ks[cur][0] + by1);
      s1 = __builtin_amdgcn_mfma_f32_32x32x16_bf16(kf1, qf[ks], s1, 0, 0, 0);
    }
    __builtin_amdgcn_s_setprio(0);

    // ==== online softmax: tree max, exp2, 4-acc tree sum ====
    float t16[16];
#pragma unroll
    for (int r = 0; r < 16; ++r) t16[r] = fmaxf(s0[r], s1[r]);
#pragma unroll
    for (int st = 8; st > 0; st >>= 1)
#pragma unroll
      for (int r = 0; r < st; ++r) t16[r] = fmaxf(t16[r], t16[r + st]);
    float tmax = fmaxf(t16[0], __shfl_xor(t16[0], 32));
    if (!__all(tmax <= m_ + 11.54f)) {   // defer-max (bound 2^11.54 = e^8)
      const float mnew = fmaxf(m_, tmax);
      const float corr = __builtin_amdgcn_exp2f(m_ - mnew);
      m_ = mnew; l_ *= corr;
#pragma unroll
      for (int r = 0; r < 16; ++r) {
        float cr = __shfl(corr, (r&3) + 8*(r>>2) + 4*hi);
        o0[r] *= cr; o1[r] *= cr;
      }
    }
    float a0 = 0.f, a1 = 0.f, a2 = 0.f, a3 = 0.f;
#pragma unroll
    for (int r = 0; r < 16; r += 4) {
      float p00 = __builtin_amdgcn_exp2f(s0[r+0] - m_);
      float p01 = __builtin_amdgcn_exp2f(s0[r+1] - m_);
      float p02 = __builtin_amdgcn_exp2f(s0[r+2] - m_);
      float p03 = __builtin_amdgcn_exp2f(s0[r+3] - m_);
      float p10 = __builtin_amdgcn_exp2f(s1[r+0] - m_);
      float p11 = __builtin_amdgcn_exp2f(s1[r+1] - m_);
      float p12 = __builtin_amdgcn_exp2f(s1[r+2] - m_);
      float p13 = __builtin_amdgcn_exp2f(s1[r+3] - m_);
      s0[r+0] = p00; s0[r+1] = p01; s0[r+2] = p02; s0[r+3] = p03;
      s1[r+0] = p10; s1[r+1] = p11; s1[r+2] = p12; s1[r+3] = p13;
      a0 += p00 + p10; a1 += p01 + p11; a2 += p02 + p12; a3 += p03 + p13;
    }
    float sum = (a0 + a1) + (a2 + a3);
    sum += __shfl_xor(sum, 32);
    l_ += sum;

    // ==== P -> bf16 PA fragments (cvt_pk + permlane32_swap) ====
    short8 pa[4];
#pragma unroll
    for (int ks2 = 0; ks2 < 2; ++ks2) {
      const int r0 = 8 * ks2;
      u32 A0 = cvtpk(s0[r0+0], s0[r0+1]), A1 = cvtpk(s0[r0+2], s0[r0+3]);
      u32 B0 = cvtpk(s0[r0+4], s0[r0+5]), B1 = cvtpk(s0[r0+6], s0[r0+7]);
      uint2v w02 = __builtin_amdgcn_permlane32_swap(A0, B0, false, false);
      uint2v w13 = __builtin_amdgcn_permlane32_swap(A1, B1, false, false);
      union { u32 w[4]; short8 v; } u_;
      u_.w[0] = w02.x; u_.w[1] = w13.x; u_.w[2] = w02.y; u_.w[3] = w13.y;
      pa[ks2] = u_.v;
    }
#pragma unroll
    for (int ks2 = 0; ks2 < 2; ++ks2) {
      const int r0 = 8 * ks2;
      u32 A0 = cvtpk(s1[r0+0], s1[r0+1]), A1 = cvtpk(s1[r0+2], s1[r0+3]);
      u32 B0 = cvtpk(s1[r0+4], s1[r0+5]), B1 = cvtpk(s1[r0+6], s1[r0+7]);
      uint2v w02 = __builtin_amdgcn_permlane32_swap(A0, B0, false, false);
      uint2v w13 = __builtin_amdgcn_permlane32_swap(A1, B1, false, false);
      union { u32 w[4]; short8 v; } u_;
      u_.w[0] = w02.x; u_.w[1] = w13.x; u_.w[2] = w02.y; u_.w[3] = w13.y;
      pa[2 + ks2] = u_.v;
    }

    // ==== O += P @ V ====
    __builtin_amdgcn_s_setprio(1);
#pragma unroll
    for (int ks = 0; ks < 4; ++ks) {
      const int vb = ks*32 + hi*16;
      const int by0 = (l31*128 + vb) ^ ((l31 & 7) << 4);
      short8 v0 = *(const short8*)((const char*)&Vs[cur][0] + by0);
      o0 = __builtin_amdgcn_mfma_f32_32x32x16_bf16(pa[ks], v0, o0, 0, 0, 0);
      const int by1 = ((32 + l31)*128 + vb) ^ ((l31 & 7) << 4);
      short8 v1 = *(const short8*)((const char*)&Vs[cur][0] + by1);
      o1 = __builtin_amdgcn_mfma_f32_32x32x16_bf16(pa[ks], v1, o1, 0, 0, 0);
    }
    __builtin_amdgcn_s_setprio(0);

    if (t < 15) {
      *(short8*)((char*)&Vs[nxt][0] + vbyt0) = ta.v;
      *(short8*)((char*)&Vs[nxt][0] + vbyt1) = tb.v;
      __syncthreads();   // drains gll16 vmcnt -> Ks[nxt] valid; orders Vs[nxt]
    }
  }

  const float linv = 1.0f / l_;
#pragma unroll
  for (int r = 0; r < 16; ++r) {
    const int rowq = (r&3) + 8*(r>>2) + 4*hi;
    const float li = __shfl(linv, rowq);
    const long srow = (long)(b * S_ + q0 + rowq);
    ob[srow * H_ + nh*HD_ + l31]      = f2b(o0[r] * li);
    ob[srow * H_ + nh*HD_ + 32 + l31] = f2b(o1[r] * li);
  }
}

// ---------------- LayerNorm over rows of H=1024 (optional pre-bias) ---------
__global__ __launch_bounds__(256)
void ln_k(const float* __restrict__ in, const float* __restrict__ g,
          const float* __restrict__ be, float* __restrict__ outf,
          u16* __restrict__ outb, const float* __restrict__ bias)
{
  const int row = blockIdx.x;
  const int tid = threadIdx.x;
  const float* x = in + (long)row * H_;
  f32x4 v = *(const f32x4*)&x[tid * 4];
  if (bias) {
    f32x4 bv = *(const f32x4*)&bias[tid * 4];
    v[0] += bv[0]; v[1] += bv[1]; v[2] += bv[2]; v[3] += bv[3];
  }
  float s  = v[0] + v[1] + v[2] + v[3];
  float ss = v[0]*v[0] + v[1]*v[1] + v[2]*v[2] + v[3]*v[3];
#pragma unroll
  for (int o = 1; o < 64; o <<= 1) {
    s  += __shfl_xor(s, o);
    ss += __shfl_xor(ss, o);
  }
  __shared__ float rs[4], rq[4];
  const int wid = tid >> 6;
  if ((tid & 63) == 0) { rs[wid] = s; rq[wid] = ss; }
  __syncthreads();
  float ts = rs[0] + rs[1] + rs[2] + rs[3];
  float tq = rq[0] + rq[1] + rq[2] + rq[3];
  const float mu = ts * (1.0f / H_);
  const float var = tq * (1.0f / H_) - mu * mu;
  const float rstd = rsqrtf(var + EPS_);
  const long obase = (long)row * H_ + tid * 4;
#pragma unroll
  for (int j = 0; j < 4; ++j) {
    int c = tid * 4 + j;
    float y = (v[j] - mu) * rstd * g[c] + be[c];
    outf[obase + j] = y;
    if (outb) outb[obase + j] = f2b(y);
  }
}

// ---------------- mean-pool over S (partials + atomic) ----------------
__global__ void pool_k(const float* __restrict__ hf, float* __restrict__ pooled) {
  const int c = blockIdx.x * 256 + threadIdx.x;
  const int b = blockIdx.y;
  const int s0 = blockIdx.z * 128;
  float s = 0.f;
  for (int t = 0; t < 128; ++t) s += hf[((long)(b * S_ + s0 + t)) * H_ + c];
  atomicAdd(&pooled[b * H_ + c], s * (1.0f / S_));
}

// ---------------- final GEMM: split-k atomic ------------------
__global__ void fgemm_k(const float* __restrict__ pooled, const float* __restrict__ W,
                        float* __restrict__ out) {
  const int n = blockIdx.x * 64 + threadIdx.x;
  const int b = blockIdx.y;
  const int k0 = blockIdx.z * 128;
  const float* pr = pooled + b * H_ + k0;
  const float* wr = W + (long)k0 * H_ + n;
  float s = 0.f;
#pragma unroll 8
  for (int k = 0; k < 128; ++k)
    s += pr[k] * wr[(long)k * H_];
  atomicAdd(&out[b * H_ + n], s);
}

extern "C" void kernel_launch(void* const* d_in, const int* in_sizes, int n_in,
                              void* d_out, int out_size, void* d_ws, size_t ws_size,
                              hipStream_t stream) {
  const float* x     = (const float*)d_in[0];
  const float* W_in  = (const float*)d_in[1];
  const float* b_in  = (const float*)d_in[2];
  const float* W_qkv = (const float*)d_in[3];
  const float* b_qkv = (const float*)d_in[4];
  const float* W_o   = (const float*)d_in[5];
  const float* b_o   = (const float*)d_in[6];
  const float* g1    = (const float*)d_in[7];
  const float* be1   = (const float*)d_in[8];
  const float* W_out = (const float*)d_in[9];
  const float* b_out = (const float*)d_in[10];
  const float* g2    = (const float*)d_in[11];
  const float* be2   = (const float*)d_in[12];
  float* outp = (float*)d_out;

  char* ws = (char*)d_ws;
  float* hf    = (float*)(ws + 0);            // 33.55 MB
  u16*   hb    = (u16*)(ws + 33554432);       // 16.78 MB
  u16*   qkvb  = (u16*)(ws + 50331648);       // 50.33 MB
  float* resf  = (float*)(ws + 50331648);     // aliases qkvb (disjoint in time)
  u16*   ob    = (u16*)(ws + 100663296);      // 16.78 MB
  u16*   xb    = (u16*)(ws + 100663296);      // aliases ob (xb dead before attn)
  u16*   WinT  = (u16*)(ws + 117440512);      // 1.05 MB
  u16*   WqkvT = (u16*)(ws + 118489088);      // 25.17 MB
  u16*   WoT   = (u16*)(ws + 143654912);      // 8.39 MB
  float* pooled= (float*)(ws + 152043520);
  float* tmpf  = (float*)(ws + 152076288);

  cvt_k<<<dim3(M_ * DIN_ / 1024), 256, 0, stream>>>(x, xb);
  tcvt_k<<<dim3(H_/32, DIN_/32, 1), 256, 0, stream>>>(W_in, WinT, DIN_, H_);
  tcvt_k<<<dim3(3*H_/32, H_/32, L_), 256, 0, stream>>>(W_qkv, WqkvT, H_, 3*H_);
  tcvt_k<<<dim3(H_/32, H_/32, L_), 256, 0, stream>>>(W_o, WoT, H_, H_);

  gemm_k<0><<<dim3(M_/128, H_/128), 256, 0, stream>>>(xb, WinT, b_in, hf, hb, nullptr, H_, DIN_, 0);

  for (int l = 0; l < L_; ++l) {
    gemm8_k<<<dim3((M_/256) * (3*H_/256)), 512, 0, stream>>>(hb, WqkvT + (size_t)l*3*H_*H_,
                                                             b_qkv + l*3*H_, qkvb);
    attn_k<<<dim3(1024), 256, 0, stream>>>(qkvb, ob);
    gemm_k<2><<<dim3(M_/128, H_/128), 256, 0, stream>>>(ob, WoT + (size_t)l*H_*H_,
                                                        b_o + l*H_, resf, nullptr, hf,
                                                        H_, H_, 0);
    ln_k<<<dim3(M_), 256, 0, stream>>>(resf, g1 + l*H_, be1 + l*H_, hf, hb, nullptr);
  }

  hipMemsetAsync(pooled, 0, B_ * H_ * sizeof(float), stream);
  hipMemsetAsync(tmpf, 0, B_ * H_ * sizeof(float), stream);
  pool_k<<<dim3(H_/256, B_, 8), 256, 0, stream>>>(hf, pooled);
  fgemm_k<<<dim3(H_/64, B_, 8), 64, 0, stream>>>(pooled, W_out, tmpf);
  ln_k<<<dim3(B_), 256, 0, stream>>>(tmpf, g2, be2, outp, nullptr, b_out);
}

// Round 11
// 873.135 us; speedup vs baseline: 1.0369x; 1.0369x over previous
//
#include <hip/hip_runtime.h>
#include <stdint.h>

typedef unsigned short u16;
typedef unsigned int   u32;
typedef __attribute__((ext_vector_type(8))) short short8;
typedef __attribute__((ext_vector_type(4))) float f32x4;
typedef __attribute__((ext_vector_type(16))) float f32x16;
typedef __attribute__((ext_vector_type(2))) unsigned int uint2v;

#define B_   8
#define S_   1024
#define DIN_ 512
#define H_   1024
#define NH_  16
#define HD_  64
#define L_   4
#define M_   (B_*S_)
#define SCALE_ 0.125f
#define LOG2E_ 1.44269504088896f
#define EPS_ 1e-5f

__device__ __forceinline__ u16 f2b(float f) {
  u32 u = __builtin_bit_cast(u32, f);
  u32 r = (u + 0x7fffu + ((u >> 16) & 1u)) >> 16;
  return (u16)r;
}

__device__ __forceinline__ u32 cvtpk(float lo, float hi) {
  u32 r;
  asm("v_cvt_pk_bf16_f32 %0, %1, %2" : "=v"(r) : "v"(lo), "v"(hi));
  return r;
}

__device__ __forceinline__ void gll16(const void* g, void* l) {
  __builtin_amdgcn_global_load_lds(
      (const __attribute__((address_space(1))) u32*)(uintptr_t)g,
      (__attribute__((address_space(3))) u32*)(uintptr_t)l,
      16, 0, 0);
}

// ---------------- fp32 -> bf16 flat convert (4 elems/thread) ----------------
__global__ void cvt_k(const float* __restrict__ in, u16* __restrict__ out) {
  long i = (long)(blockIdx.x * 256 + threadIdx.x) * 4;
  f32x4 v = *(const f32x4*)&in[i];
  u32 p0 = (u32)f2b(v[0]) | ((u32)f2b(v[1]) << 16);
  u32 p1 = (u32)f2b(v[2]) | ((u32)f2b(v[3]) << 16);
  u32* o = (u32*)&out[i];
  o[0] = p0; o[1] = p1;
}

// -------- fp32 [R,C] -> bf16 [C,R] transpose-convert, batched over z --------
__global__ __launch_bounds__(256)
void tcvt_k(const float* __restrict__ in0, u16* __restrict__ out0, int R, int C) {
  __shared__ float t[32][33];
  const float* in = in0 + (size_t)blockIdx.z * R * C;
  u16* out = out0 + (size_t)blockIdx.z * R * C;
  int tx = threadIdx.x & 31, ty = threadIdx.x >> 5;
  long r0 = blockIdx.y * 32, c0 = blockIdx.x * 32;
#pragma unroll
  for (int i = 0; i < 4; ++i)
    t[ty + i*8][tx] = in[(r0 + ty + i*8) * (long)C + c0 + tx];
  __syncthreads();
#pragma unroll
  for (int i = 0; i < 4; ++i)
    out[(c0 + ty + i*8) * (long)R + r0 + tx] = f2b(t[tx][ty + i*8]);
}

// ---------------- 128x128 GEMM (in-proj / O-proj): simple 2-barrier --------
template<int EPI>
__global__ __launch_bounds__(256, 2)
void gemm_k(const u16* __restrict__ A, const u16* __restrict__ Bt,
            const float* __restrict__ bias,
            float* __restrict__ Cf, u16* __restrict__ Cb,
            const float* __restrict__ Res,
            int Ndim, int K, int scale_cols)
{
  __shared__ u16 As[128 * 32];
  __shared__ u16 Bs[128 * 32];
  const int tid = threadIdx.x;
  const int lane = tid & 63;
  const int wid = tid >> 6;
  const int wr = wid >> 1, wc = wid & 1;
  const int l15 = lane & 15, l4 = lane >> 4;
  const long arow0 = (long)blockIdx.x * 128;
  const long brow0 = (long)blockIdx.y * 128;

  f32x4 acc[4][4] = {};

  const int srow = tid >> 2;
  const int scol = (tid & 3) * 8;
  const u16* ga  = A  + (arow0 + srow) * K + scol;
  const u16* ga1 = ga + 64 * (long)K;
  const u16* gb  = Bt + (brow0 + srow) * K + scol;
  const u16* gb1 = gb + 64 * (long)K;
  u16* lA0 = &As[tid * 8];
  u16* lA1 = &As[2048 + tid * 8];
  u16* lB0 = &Bs[tid * 8];
  u16* lB1 = &Bs[2048 + tid * 8];

  for (int k0 = 0; k0 < K; k0 += 32) {
    gll16(ga + k0, lA0);
    gll16(ga1 + k0, lA1);
    gll16(gb + k0, lB0);
    gll16(gb1 + k0, lB1);
    __syncthreads();
    short8 af[4], bf[4];
#pragma unroll
    for (int m = 0; m < 4; ++m)
      af[m] = *(const short8*)&As[(wr*64 + m*16 + l15) * 32 + l4*8];
#pragma unroll
    for (int n = 0; n < 4; ++n)
      bf[n] = *(const short8*)&Bs[(wc*64 + n*16 + l15) * 32 + l4*8];
#pragma unroll
    for (int m = 0; m < 4; ++m)
#pragma unroll
      for (int n = 0; n < 4; ++n)
        acc[m][n] = __builtin_amdgcn_mfma_f32_16x16x32_bf16(af[m], bf[n], acc[m][n], 0, 0, 0);
    __syncthreads();
  }

  const int crow = wr*64 + l4*4;
  const int ccol = wc*64 + l15;
#pragma unroll
  for (int m = 0; m < 4; ++m) {
#pragma unroll
    for (int n = 0; n < 4; ++n) {
      const int col = (int)brow0 + ccol + n*16;
      const float bv = bias[col];
      const float sc = (EPI == 1 && col < scale_cols) ? SCALE_ : 1.0f;
#pragma unroll
      for (int r = 0; r < 4; ++r) {
        const long row = arow0 + crow + m*16 + r;
        float v = acc[m][n][r] + bv;
        if (EPI == 1) {
          Cb[row * Ndim + col] = f2b(v * sc);
        } else if (EPI == 0) {
          Cf[row * Ndim + col] = v;
          Cb[row * Ndim + col] = f2b(v);
        } else {
          Cf[row * Ndim + col] = v + Res[row * Ndim + col];
        }
      }
    }
  }
}

// ---------------- 256x256 8-phase GEMM for QKV (M=8192,N=3072,K=1024) -------
// Q columns pre-scaled by SCALE_*log2(e) so attention works in exp2 domain.
__global__ __launch_bounds__(512, 1)
void gemm8_k(const u16* __restrict__ A, const u16* __restrict__ Bt,
             const float* __restrict__ bias, u16* __restrict__ Cb)
{
  constexpr int K = 1024, N = 3 * H_;
  constexpr int NT = K / 64;                 // 16 K-tiles
  __shared__ u16 lds[8][8192];               // [buf*4 + op*2 + half][128*64]

  const int tid = threadIdx.x;
  const int lane = tid & 63;
  const int wid = tid >> 6;
  const int wm = wid >> 2, wn = wid & 3;
  const int l15 = lane & 15, l4 = lane >> 4;

  const int bid = blockIdx.x;                // 384 blocks
  const int xcd = bid & 7, idx = bid >> 3;   // XCD owns arow strip of 4
  const long arow0 = (long)(xcd * 4 + (idx & 3)) * 256;
  const long brow0 = (long)(idx >> 2) * 256;

  f32x4 acc[8][4] = {};
  short8 bfr[4][2];
  short8 afr[2][2];

  auto stage = [&](int buf, int op, int half, int kt) {
    const u16* src = op ? Bt : A;
    const long rb = (op ? brow0 : arow0) + half * 128;
    u16* dst = lds[buf*4 + op*2 + half];
#pragma unroll
    for (int ld = 0; ld < 2; ++ld) {
      int p = ld * 512 + tid;
      int row = p >> 3;
      int kc = (p & 7) ^ (row & 7);          // inverse swizzle on source
      gll16(src + (rb + row) * (long)K + kt * 64 + kc * 8, (char*)dst + p * 16);
    }
  };
  auto readB = [&](int buf) {
    const char* base = (const char*)lds[buf*4 + 2 + (wn >> 1)];
#pragma unroll
    for (int n = 0; n < 4; ++n)
#pragma unroll
      for (int ks = 0; ks < 2; ++ks) {
        int rh = (wn & 1) * 64 + n * 16 + l15;
        int byt = rh * 128 + ((((ks*4 + l4) * 16)) ^ ((rh & 7) << 4));
        bfr[n][ks] = *(const short8*)(base + byt);
      }
  };
  auto readA = [&](int buf, int q) {
    const char* base = (const char*)lds[buf*4 + wm];
#pragma unroll
    for (int j = 0; j < 2; ++j)
#pragma unroll
      for (int ks = 0; ks < 2; ++ks) {
        int rh = (2*q + j) * 16 + l15;
        int byt = rh * 128 + ((((ks*4 + l4) * 16)) ^ ((rh & 7) << 4));
        afr[j][ks] = *(const short8*)(base + byt);
      }
  };
  auto mm = [&](int q) {
    __builtin_amdgcn_s_setprio(1);
#pragma unroll
    for (int j = 0; j < 2; ++j)
#pragma unroll
      for (int n = 0; n < 4; ++n)
#pragma unroll
        for (int ks = 0; ks < 2; ++ks)
          acc[2*q+j][n] = __builtin_amdgcn_mfma_f32_16x16x32_bf16(
              afr[j][ks], bfr[n][ks], acc[2*q+j][n], 0, 0, 0);
    __builtin_amdgcn_s_setprio(0);
  };

#define PH(cb, q, doB, sb, so, sh, st, doV)                       \
    readA(cb, q); if (doB) readB(cb);                             \
    stage(sb, so, sh, st);                                        \
    __builtin_amdgcn_s_barrier();                                 \
    mm(q);                                                        \
    if (doV) asm volatile("s_waitcnt vmcnt(6)" ::: "memory");     \
    __builtin_amdgcn_s_barrier();

  // prologue: B0,B1,A0,A1(tile0)->buf0; B0,B1,A0(tile1)->buf1  (7 half-tiles)
  stage(0,1,0,0); stage(0,1,1,0); stage(0,0,0,0); stage(0,0,1,0);
  stage(1,1,0,1); stage(1,1,1,1); stage(1,0,0,1);
  asm volatile("s_waitcnt vmcnt(6)" ::: "memory");   // buf0 (tile0) landed
  __builtin_amdgcn_s_barrier();

  const int niter = NT / 2;
  for (int i = 0; i < niter; ++i) {
    const int tO  = 2*i + 1;
    const int tE2 = (2*i + 2 < NT) ? 2*i + 2 : NT - 1;
    const int tO2 = (2*i + 3 < NT) ? 2*i + 3 : NT - 1;
    PH(0, 0, true , 1, 0, 1, tO , false)
    PH(0, 1, false, 0, 1, 0, tE2, false)
    PH(0, 2, false, 0, 1, 1, tE2, false)
    PH(0, 3, false, 0, 0, 0, tE2, true )
    PH(1, 0, true , 0, 0, 1, tE2, false)
    PH(1, 1, false, 1, 1, 0, tO2, false)
    PH(1, 2, false, 1, 1, 1, tO2, false)
    PH(1, 3, false, 1, 0, 0, tO2, true )
  }
#undef PH

  const long crow0 = arow0 + wm * 128;
  const int  ccol0 = (int)brow0 + wn * 64;
#pragma unroll
  for (int m = 0; m < 8; ++m) {
#pragma unroll
    for (int n = 0; n < 4; ++n) {
      const int col = ccol0 + n * 16 + l15;
      const float bv = bias[col];
      const float sc = (col < H_) ? (SCALE_ * LOG2E_) : 1.0f;
#pragma unroll
      for (int r = 0; r < 4; ++r) {
        const long row = crow0 + m * 16 + l4 * 4 + r;
        Cb[row * N + col] = f2b((acc[m][n][r] + bv) * sc);
      }
    }
  }
}

// ------------- flash attention v5: 8-wave structure (r9) + exp2/tree softmax
// grid: 512 blocks x 512 threads (8 waves x 32 q-rows = 256 q/block).
// Swapped QK^T (A=K,B=Q); softmax in-lane in log2 domain (Q pre-scaled).
__global__ __launch_bounds__(512)
void attn_k(const u16* __restrict__ qkv, u16* __restrict__ ob)
{
  __shared__ u16 Ks[2][4096];   // [64 kv][64 d], XOR-swizzled content
  __shared__ u16 Vs[2][4096];   // [64 d][64 kv] transposed, XOR-swizzled

  const int tid = threadIdx.x, lane = tid & 63, wid = tid >> 6;
  const int l31 = lane & 31, hi = lane >> 5;

  const int blk = blockIdx.x;
  const int xcd = blk & 7, slot = blk >> 3;
  const int bh = xcd + ((slot >> 2) << 3);   // head 0..127
  const int qx = slot & 3;                   // q-tile 0..3 (256 rows each)
  const int b = bh >> 4, nh = bh & 15;
  const int q0 = qx * 256 + wid * 32;

  const int RS = 3 * H_;
  const long base = (long)b * S_ * RS;
  const u16* Qg = qkv + base + nh * HD_;
  const u16* Kg = qkv + base + H_ + nh * HD_;
  const u16* Vg = qkv + base + 2 * H_ + nh * HD_;

  short8 qf[4];
#pragma unroll
  for (int ks = 0; ks < 4; ++ks)
    qf[ks] = *(const short8*)&Qg[(long)(q0 + l31) * RS + ks*16 + hi*8];

  float m_ = -1e30f, l_ = 0.f;
  f32x16 o0 = {}, o1 = {};

  const int krow = tid >> 3, kc = tid & 7;
  const int ksc = kc ^ (krow & 7);
  const long kgoff = (long)krow * RS + ksc * 8;
  const int vd = tid & 63, vch = tid >> 6;
  const int vbyt = (vd*128 + vch*16) ^ ((vd & 7) << 4);

  {
    gll16(Kg + kgoff, (char*)&Ks[0][0] + tid*16);
    union { u16 u[8]; short8 v; } tv;
#pragma unroll
    for (int j = 0; j < 8; ++j)
      tv.u[j] = Vg[(long)(vch*8 + j) * RS + vd];
    *(short8*)((char*)&Vs[0][0] + vbyt) = tv.v;
  }
  __syncthreads();

  for (int t = 0; t < 16; ++t) {
    const int cur = t & 1, nxt = cur ^ 1;
    union { u16 u[8]; short8 v; } ta;
    if (t < 15) {
      const long kv1 = (long)(t + 1) * 64;
      gll16(Kg + kv1 * RS + kgoff, (char*)&Ks[nxt][0] + tid*16);
#pragma unroll
      for (int j = 0; j < 8; ++j)
        ta.u[j] = Vg[(kv1 + vch*8 + j) * RS + vd];
    }

    // ==== QK^T (log2-domain scores; Q pre-scaled by SCALE*log2e) ====
    f32x16 s0 = {}, s1 = {};
    __builtin_amdgcn_s_setprio(1);
#pragma unroll
    for (int ks = 0; ks < 4; ++ks) {
      const int koff = ks*32 + hi*16;
      const int by0 = (l31*128 + koff) ^ ((l31 & 7) << 4);
      short8 kf0 = *(const short8*)((const char*)&Ks[cur][0] + by0);
      s0 = __builtin_amdgcn_mfma_f32_32x32x16_bf16(kf0, qf[ks], s0, 0, 0, 0);
      const int by1 = ((32 + l31)*128 + koff) ^ ((l31 & 7) << 4);
      short8 kf1 = *(const short8*)((const char*)&Ks[cur][0] + by1);
      s1 = __builtin_amdgcn_mfma_f32_32x32x16_bf16(kf1, qf[ks], s1, 0, 0, 0);
    }
    __builtin_amdgcn_s_setprio(0);

    // ==== softmax: 8-temp tree max, exp2, 4-acc tree sum ====
    float t8[8];
#pragma unroll
    for (int r = 0; r < 8; ++r)
      t8[r] = fmaxf(fmaxf(s0[2*r], s0[2*r+1]), fmaxf(s1[2*r], s1[2*r+1]));
    t8[0] = fmaxf(t8[0], t8[4]); t8[1] = fmaxf(t8[1], t8[5]);
    t8[2] = fmaxf(t8[2], t8[6]); t8[3] = fmaxf(t8[3], t8[7]);
    t8[0] = fmaxf(fmaxf(t8[0], t8[1]), fmaxf(t8[2], t8[3]));
    float tmax = fmaxf(t8[0], __shfl_xor(t8[0], 32));
    if (!__all(tmax <= m_ + 11.54f)) {   // defer-max (2^11.54 = e^8 bound)
      const float mnew = fmaxf(m_, tmax);
      const float corr = __builtin_amdgcn_exp2f(m_ - mnew);
      m_ = mnew; l_ *= corr;
#pragma unroll
      for (int r = 0; r < 16; ++r) {
        float cr = __shfl(corr, (r&3) + 8*(r>>2) + 4*hi);
        o0[r] *= cr; o1[r] *= cr;
      }
    }
    float a0 = 0.f, a1 = 0.f, a2 = 0.f, a3 = 0.f;
#pragma unroll
    for (int r = 0; r < 16; r += 4) {
      float p00 = __builtin_amdgcn_exp2f(s0[r+0] - m_);
      float p01 = __builtin_amdgcn_exp2f(s0[r+1] - m_);
      float p02 = __builtin_amdgcn_exp2f(s0[r+2] - m_);
      float p03 = __builtin_amdgcn_exp2f(s0[r+3] - m_);
      float p10 = __builtin_amdgcn_exp2f(s1[r+0] - m_);
      float p11 = __builtin_amdgcn_exp2f(s1[r+1] - m_);
      float p12 = __builtin_amdgcn_exp2f(s1[r+2] - m_);
      float p13 = __builtin_amdgcn_exp2f(s1[r+3] - m_);
      s0[r+0] = p00; s0[r+1] = p01; s0[r+2] = p02; s0[r+3] = p03;
      s1[r+0] = p10; s1[r+1] = p11; s1[r+2] = p12; s1[r+3] = p13;
      a0 += p00 + p10; a1 += p01 + p11; a2 += p02 + p12; a3 += p03 + p13;
    }
    float sum = (a0 + a1) + (a2 + a3);
    sum += __shfl_xor(sum, 32);
    l_ += sum;

    // ==== P -> bf16 PA fragments (cvt_pk + permlane32_swap) ====
    short8 pa[4];
#pragma unroll
    for (int ks2 = 0; ks2 < 2; ++ks2) {
      const int r0 = 8 * ks2;
      u32 A0 = cvtpk(s0[r0+0], s0[r0+1]), A1 = cvtpk(s0[r0+2], s0[r0+3]);
      u32 B0 = cvtpk(s0[r0+4], s0[r0+5]), B1 = cvtpk(s0[r0+6], s0[r0+7]);
      uint2v w02 = __builtin_amdgcn_permlane32_swap(A0, B0, false, false);
      uint2v w13 = __builtin_amdgcn_permlane32_swap(A1, B1, false, false);
      union { u32 w[4]; short8 v; } u_;
      u_.w[0] = w02.x; u_.w[1] = w13.x; u_.w[2] = w02.y; u_.w[3] = w13.y;
      pa[ks2] = u_.v;
    }
#pragma unroll
    for (int ks2 = 0; ks2 < 2; ++ks2) {
      const int r0 = 8 * ks2;
      u32 A0 = cvtpk(s1[r0+0], s1[r0+1]), A1 = cvtpk(s1[r0+2], s1[r0+3]);
      u32 B0 = cvtpk(s1[r0+4], s1[r0+5]), B1 = cvtpk(s1[r0+6], s1[r0+7]);
      uint2v w02 = __builtin_amdgcn_permlane32_swap(A0, B0, false, false);
      uint2v w13 = __builtin_amdgcn_permlane32_swap(A1, B1, false, false);
      union { u32 w[4]; short8 v; } u_;
      u_.w[0] = w02.x; u_.w[1] = w13.x; u_.w[2] = w02.y; u_.w[3] = w13.y;
      pa[2 + ks2] = u_.v;
    }

    // ==== O += P @ V ====
    __builtin_amdgcn_s_setprio(1);
#pragma unroll
    for (int ks = 0; ks < 4; ++ks) {
      const int vb = ks*32 + hi*16;
      const int by0 = (l31*128 + vb) ^ ((l31 & 7) << 4);
      short8 v0 = *(const short8*)((const char*)&Vs[cur][0] + by0);
      o0 = __builtin_amdgcn_mfma_f32_32x32x16_bf16(pa[ks], v0, o0, 0, 0, 0);
      const int by1 = ((32 + l31)*128 + vb) ^ ((l31 & 7) << 4);
      short8 v1 = *(const short8*)((const char*)&Vs[cur][0] + by1);
      o1 = __builtin_amdgcn_mfma_f32_32x32x16_bf16(pa[ks], v1, o1, 0, 0, 0);
    }
    __builtin_amdgcn_s_setprio(0);

    if (t < 15) {
      *(short8*)((char*)&Vs[nxt][0] + vbyt) = ta.v;
      __syncthreads();
    }
  }

  const float linv = 1.0f / l_;
#pragma unroll
  for (int r = 0; r < 16; ++r) {
    const int rowq = (r&3) + 8*(r>>2) + 4*hi;
    const float li = __shfl(linv, rowq);
    const long srow = (long)(b * S_ + q0 + rowq);
    ob[srow * H_ + nh*HD_ + l31]      = f2b(o0[r] * li);
    ob[srow * H_ + nh*HD_ + 32 + l31] = f2b(o1[r] * li);
  }
}

// ---------------- LayerNorm over rows of H=1024 (optional pre-bias) ---------
__global__ __launch_bounds__(256)
void ln_k(const float* __restrict__ in, const float* __restrict__ g,
          const float* __restrict__ be, float* __restrict__ outf,
          u16* __restrict__ outb, const float* __restrict__ bias)
{
  const int row = blockIdx.x;
  const int tid = threadIdx.x;
  const float* x = in + (long)row * H_;
  f32x4 v = *(const f32x4*)&x[tid * 4];
  if (bias) {
    f32x4 bv = *(const f32x4*)&bias[tid * 4];
    v[0] += bv[0]; v[1] += bv[1]; v[2] += bv[2]; v[3] += bv[3];
  }
  float s  = v[0] + v[1] + v[2] + v[3];
  float ss = v[0]*v[0] + v[1]*v[1] + v[2]*v[2] + v[3]*v[3];
#pragma unroll
  for (int o = 1; o < 64; o <<= 1) {
    s  += __shfl_xor(s, o);
    ss += __shfl_xor(ss, o);
  }
  __shared__ float rs[4], rq[4];
  const int wid = tid >> 6;
  if ((tid & 63) == 0) { rs[wid] = s; rq[wid] = ss; }
  __syncthreads();
  float ts = rs[0] + rs[1] + rs[2] + rs[3];
  float tq = rq[0] + rq[1] + rq[2] + rq[3];
  const float mu = ts * (1.0f / H_);
  const float var = tq * (1.0f / H_) - mu * mu;
  const float rstd = rsqrtf(var + EPS_);
  const long obase = (long)row * H_ + tid * 4;
#pragma unroll
  for (int j = 0; j < 4; ++j) {
    int c = tid * 4 + j;
    float y = (v[j] - mu) * rstd * g[c] + be[c];
    outf[obase + j] = y;
    if (outb) outb[obase + j] = f2b(y);
  }
}

// ---------------- mean-pool over S (partials + atomic) ----------------
__global__ void pool_k(const float* __restrict__ hf, float* __restrict__ pooled) {
  const int c = blockIdx.x * 256 + threadIdx.x;
  const int b = blockIdx.y;
  const int s0 = blockIdx.z * 128;
  float s = 0.f;
  for (int t = 0; t < 128; ++t) s += hf[((long)(b * S_ + s0 + t)) * H_ + c];
  atomicAdd(&pooled[b * H_ + c], s * (1.0f / S_));
}

// ---------------- final GEMM: split-k atomic ------------------
__global__ void fgemm_k(const float* __restrict__ pooled, const float* __restrict__ W,
                        float* __restrict__ out) {
  const int n = blockIdx.x * 64 + threadIdx.x;
  const int b = blockIdx.y;
  const int k0 = blockIdx.z * 128;
  const float* pr = pooled + b * H_ + k0;
  const float* wr = W + (long)k0 * H_ + n;
  float s = 0.f;
#pragma unroll 8
  for (int k = 0; k < 128; ++k)
    s += pr[k] * wr[(long)k * H_];
  atomicAdd(&out[b * H_ + n], s);
}

extern "C" void kernel_launch(void* const* d_in, const int* in_sizes, int n_in,
                              void* d_out, int out_size, void* d_ws, size_t ws_size,
                              hipStream_t stream) {
  const float* x     = (const float*)d_in[0];
  const float* W_in  = (const float*)d_in[1];
  const float* b_in  = (const float*)d_in[2];
  const float* W_qkv = (const float*)d_in[3];
  const float* b_qkv = (const float*)d_in[4];
  const float* W_o   = (const float*)d_in[5];
  const float* b_o   = (const float*)d_in[6];
  const float* g1    = (const float*)d_in[7];
  const float* be1   = (const float*)d_in[8];
  const float* W_out = (const float*)d_in[9];
  const float* b_out = (const float*)d_in[10];
  const float* g2    = (const float*)d_in[11];
  const float* be2   = (const float*)d_in[12];
  float* outp = (float*)d_out;

  char* ws = (char*)d_ws;
  float* hf    = (float*)(ws + 0);            // 33.55 MB
  u16*   hb    = (u16*)(ws + 33554432);       // 16.78 MB
  u16*   qkvb  = (u16*)(ws + 50331648);       // 50.33 MB
  float* resf  = (float*)(ws + 50331648);     // aliases qkvb (disjoint in time)
  u16*   ob    = (u16*)(ws + 100663296);      // 16.78 MB
  u16*   xb    = (u16*)(ws + 100663296);      // aliases ob (xb dead before attn)
  u16*   WinT  = (u16*)(ws + 117440512);      // 1.05 MB
  u16*   WqkvT = (u16*)(ws + 118489088);      // 25.17 MB
  u16*   WoT   = (u16*)(ws + 143654912);      // 8.39 MB
  float* pooled= (float*)(ws + 152043520);
  float* tmpf  = (float*)(ws + 152076288);

  cvt_k<<<dim3(M_ * DIN_ / 1024), 256, 0, stream>>>(x, xb);
  tcvt_k<<<dim3(H_/32, DIN_/32, 1), 256, 0, stream>>>(W_in, WinT, DIN_, H_);
  tcvt_k<<<dim3(3*H_/32, H_/32, L_), 256, 0, stream>>>(W_qkv, WqkvT, H_, 3*H_);
  tcvt_k<<<dim3(H_/32, H_/32, L_), 256, 0, stream>>>(W_o, WoT, H_, H_);

  gemm_k<0><<<dim3(M_/128, H_/128), 256, 0, stream>>>(xb, WinT, b_in, hf, hb, nullptr, H_, DIN_, 0);

  for (int l = 0; l < L_; ++l) {
    gemm8_k<<<dim3((M_/256) * (3*H_/256)), 512, 0, stream>>>(hb, WqkvT + (size_t)l*3*H_*H_,
                                                             b_qkv + l*3*H_, qkvb);
    attn_k<<<dim3(512), 512, 0, stream>>>(qkvb, ob);
    gemm_k<2><<<dim3(M_/128, H_/128), 256, 0, stream>>>(ob, WoT + (size_t)l*H_*H_,
                                                        b_o + l*H_, resf, nullptr, hf,
                                                        H_, H_, 0);
    ln_k<<<dim3(M_), 256, 0, stream>>>(resf, g1 + l*H_, be1 + l*H_, hf, hb, nullptr);
  }

  hipMemsetAsync(pooled, 0, B_ * H_ * sizeof(float), stream);
  hipMemsetAsync(tmpf, 0, B_ * H_ * sizeof(float), stream);
  pool_k<<<dim3(H_/256, B_, 8), 256, 0, stream>>>(hf, pooled);
  fgemm_k<<<dim3(H_/64, B_, 8), 64, 0, stream>>>(pooled, W_out, tmpf);
  ln_k<<<dim3(B_), 256, 0, stream>>>(tmpf, g2, be2, outp, nullptr, b_out);
}